// Round 6
// baseline (249.415 us; speedup 1.0000x reference)
//
#include <hip/hip_runtime.h>
#include <hip/hip_bf16.h>

#define KE_F  332.0636f
#define MAX_M 1024   // padded molecule count (harness M = 1000)
#define BLK   256
#define NBLK  2048

typedef int   ivec4 __attribute__((ext_vector_type(4)));
typedef float fvec4 __attribute__((ext_vector_type(4)));

__device__ __forceinline__ float softplusf(float x) {
    return logf(1.0f + expf(x));
}

// One block: prefix-scan num_atoms -> mol_starts[M+1]; derived constants into
// params: [0..3]=c_k/sum(c), [4..7]=exponents_k/d, [16..111]=Z^zexp table;
// also zeroes out[0..M) (harness re-poisons d_out to 0xAA each launch).
__global__ void scan_params_kernel(const int* __restrict__ num_atoms, int M,
                                   const float* __restrict__ d_inv,
                                   const float* __restrict__ z_exp_inv,
                                   const float* __restrict__ c_inv,
                                   const float* __restrict__ exp_inv,
                                   int* __restrict__ mol_starts,
                                   float* __restrict__ params,
                                   float* __restrict__ out) {
    __shared__ int buf[MAX_M];
    int t = threadIdx.x;
    buf[t] = (t < M) ? num_atoms[t] : 0;
    __syncthreads();
    for (int off = 1; off < MAX_M; off <<= 1) {   // Hillis-Steele inclusive scan
        int x = (t >= off) ? buf[t - off] : 0;
        __syncthreads();
        buf[t] += x;
        __syncthreads();
    }
    if (t == 0) mol_starts[0] = 0;
    if (t < M) mol_starts[t + 1] = buf[t];
    if (t == 0) {
        float dd = softplusf(d_inv[0]);
        float c0 = softplusf(c_inv[0]), c1 = softplusf(c_inv[1]);
        float c2 = softplusf(c_inv[2]), c3 = softplusf(c_inv[3]);
        float e0 = softplusf(exp_inv[0]), e1 = softplusf(exp_inv[1]);
        float e2 = softplusf(exp_inv[2]), e3 = softplusf(exp_inv[3]);
        float ic = 1.0f / (c0 + c1 + c2 + c3);
        float id = 1.0f / dd;
        params[0] = c0 * ic; params[1] = c1 * ic; params[2] = c2 * ic; params[3] = c3 * ic;
        params[4] = e0 * id; params[5] = e1 * id; params[6] = e2 * id; params[7] = e3 * id;
    }
    if (t < 96) {                                  // z in [1,94): table of Z^zexp
        float zexp = softplusf(z_exp_inv[0]);
        params[16 + t] = __powf((float)t, zexp);
    }
    for (int k = t; k < M; k += MAX_M) out[k] = 0.0f;
}

// Per-atom packing: pack[a] = (x, y, z, encode(mol, Z)) where
// encode = float((mol << 7) | Z)  (exact: < 2^17). mol via binary search on
// mol_starts (clamps to M-1, matching jnp.repeat total_repeat_length pad).
__global__ void pack_kernel(const float* __restrict__ xyz,
                            const int* __restrict__ z,
                            const int* __restrict__ mol_starts, int M, int N,
                            float4* __restrict__ pack) {
    int a = blockIdx.x * blockDim.x + threadIdx.x;
    if (a >= N) return;
    int lo = 0, hi = M;
    while (hi - lo > 1) {
        int mid = (lo + hi) >> 1;
        if (mol_starts[mid] <= a) lo = mid; else hi = mid;
    }
    pack[a] = make_float4(xyz[3 * a + 0], xyz[3 * a + 1], xyz[3 * a + 2],
                          (float)((lo << 7) | z[a]));
}

struct Stream {                // one 4-edge group's streamed data
    ivec4 n01, n23;            // 4 (i,j) pairs
    fvec4 oA, oB, oC;          // 12 offset floats
};

struct Gathered {
    float4 pi[4], pj[4];
    bool   m[4];
};

__device__ __forceinline__ Stream load_stream(const ivec4* __restrict__ nb4,
                                              const fvec4* __restrict__ of4,
                                              size_t g) {
    Stream s;
    s.n01 = __builtin_nontemporal_load(nb4 + 2 * g);
    s.n23 = __builtin_nontemporal_load(nb4 + 2 * g + 1);
    s.oA  = __builtin_nontemporal_load(of4 + 3 * g);
    s.oB  = __builtin_nontemporal_load(of4 + 3 * g + 1);
    s.oC  = __builtin_nontemporal_load(of4 + 3 * g + 2);
    return s;
}

__device__ __forceinline__ Gathered do_gather(const Stream& s,
                                              const float4* __restrict__ pack) {
    Gathered d;
    const int iv[4] = {s.n01.x, s.n01.z, s.n23.x, s.n23.z};
    const int jv[4] = {s.n01.y, s.n01.w, s.n23.y, s.n23.w};
#pragma unroll
    for (int k = 0; k < 4; ++k) {          // batched, branch-free gathers
        d.m[k] = jv[k] > iv[k];
        d.pi[k] = pack[d.m[k] ? iv[k] : 0];   // masked lanes broadcast line 0
        d.pj[k] = pack[d.m[k] ? jv[k] : 0];
    }
    return d;
}

__device__ __forceinline__ void compute4(const Gathered& d, const Stream& s,
                                         float4 kk, float4 gg,
                                         const float* __restrict__ zp,
                                         float* __restrict__ sm) {
    const float ox[4] = {s.oA.x, s.oA.w, s.oB.z, s.oC.y};
    const float oy[4] = {s.oA.y, s.oB.x, s.oB.w, s.oC.z};
    const float oz[4] = {s.oA.z, s.oB.y, s.oC.x, s.oC.w};
#pragma unroll
    for (int k = 0; k < 4; ++k) {
        const float dx = d.pi[k].x - d.pj[k].x - ox[k];
        const float dy = d.pi[k].y - d.pj[k].y - oy[k];
        const float dz = d.pi[k].z - d.pj[k].z - oz[k];
        const float r2 = fmaf(dx, dx, fmaf(dy, dy, dz * dz)) + 3e-15f;
        const bool ok = d.m[k] && (r2 < 25.0f);
        const int  wi = (int)d.pi[k].w;
        const int  wj = (int)d.pj[k].w;
        const float inv_r = rsqrtf(r2);
        const float rs = r2 * inv_r * (zp[wi & 127] + zp[wj & 127]);
        const float u  = __fdividef(r2, 25.0f - r2);      // f_cut folded into exps
        const float pf = kk.x * __expf(fmaf(-gg.x, rs, -u)) +
                         kk.y * __expf(fmaf(-gg.y, rs, -u)) +
                         kk.z * __expf(fmaf(-gg.z, rs, -u)) +
                         kk.w * __expf(fmaf(-gg.w, rs, -u));
        const float val = KE_F * (float)(wi & 127) * (float)(wj & 127) * inv_r * pf;
        if (ok) atomicAdd(&sm[wi >> 7], val);   // inf/nan of dead lanes discarded
    }
}

__global__ __launch_bounds__(BLK) void nr_main_kernel(
    const int* __restrict__ nbrs, const float* __restrict__ offsets,
    const float4* __restrict__ pack,
    const float* __restrict__ params, float* __restrict__ out, int E, int M) {
    __shared__ float sm[MAX_M];
    __shared__ float zp[96];
    for (int t = threadIdx.x; t < MAX_M; t += BLK) sm[t] = 0.0f;
    if (threadIdx.x < 96) zp[threadIdx.x] = params[16 + threadIdx.x];
    __syncthreads();

    const float4 kk = *(const float4*)(params + 0);   // phi coefficients
    const float4 gg = *(const float4*)(params + 4);   // exponent scales (/d folded)

    const int ngroups = E >> 2;                       // 4 edges per group
    const int stride  = gridDim.x * BLK;
    const ivec4* nb4 = (const ivec4*)nbrs;
    const fvec4* of4 = (const fvec4*)offsets;

    int g = blockIdx.x * BLK + threadIdx.x;
    if (g < ngroups) {
        const size_t last = (size_t)(ngroups - 1);
        // ---- 2-deep software pipeline: stream g+2s | gather g+s | compute g.
        // Out-of-range prefetches clamp to `last`: all lanes collapse onto the
        // same cache lines (broadcast) -> negligible extra traffic, no branches.
        size_t g1 = (size_t)g + stride; if (g1 > last) g1 = last;
        Stream s_cur = load_stream(nb4, of4, (size_t)g);
        Stream s_nxt = load_stream(nb4, of4, g1);
        Gathered d_cur = do_gather(s_cur, pack);
        for (;;) {
            size_t g2 = (size_t)g + 2 * (size_t)stride; if (g2 > last) g2 = last;
            Stream   s_n2  = load_stream(nb4, of4, g2);
            Gathered d_nxt = do_gather(s_nxt, pack);
            compute4(d_cur, s_cur, kk, gg, zp, sm);
            const int gn = g + stride;
            if (gn >= ngroups) break;
            g = gn;
            s_cur = s_nxt; s_nxt = s_n2; d_cur = d_nxt;
        }
    }

    // Tail edges [4*ngroups, E) — scalar path (E%4, usually empty).
    for (int e = (ngroups << 2) + blockIdx.x * BLK + threadIdx.x; e < E; e += stride) {
        const int i = nbrs[2 * e], j = nbrs[2 * e + 1];
        if (j <= i) continue;
        const float oxs = offsets[3 * e], oys = offsets[3 * e + 1], ozs = offsets[3 * e + 2];
        const float4 pis = pack[i], pjs = pack[j];
        const float dx = pis.x - pjs.x - oxs;
        const float dy = pis.y - pjs.y - oys;
        const float dz = pis.z - pjs.z - ozs;
        const float r2 = fmaf(dx, dx, fmaf(dy, dy, dz * dz)) + 3e-15f;
        if (r2 >= 25.0f) continue;
        const int  wi = (int)pis.w;
        const int  wj = (int)pjs.w;
        const float inv_r = rsqrtf(r2);
        const float rs = r2 * inv_r * (zp[wi & 127] + zp[wj & 127]);
        const float u  = __fdividef(r2, 25.0f - r2);
        const float pf = kk.x * __expf(fmaf(-gg.x, rs, -u)) +
                         kk.y * __expf(fmaf(-gg.y, rs, -u)) +
                         kk.z * __expf(fmaf(-gg.z, rs, -u)) +
                         kk.w * __expf(fmaf(-gg.w, rs, -u));
        atomicAdd(&sm[wi >> 7],
                  KE_F * (float)(wi & 127) * (float)(wj & 127) * inv_r * pf);
    }

    __syncthreads();
    // Sparse flush: ~35% of slots nonzero per block -> ~0.7M global atomics total.
    for (int t = threadIdx.x; t < M; t += BLK) {
        const float v = sm[t];
        if (v != 0.0f) atomicAdd(&out[t], v);
    }
}

extern "C" void kernel_launch(void* const* d_in, const int* in_sizes, int n_in,
                              void* d_out, int out_size, void* d_ws, size_t ws_size,
                              hipStream_t stream) {
    const float* xyz       = (const float*)d_in[0];
    const int*   z         = (const int*)d_in[1];
    const int*   nbrs      = (const int*)d_in[2];
    const int*   num_atoms = (const int*)d_in[3];
    const float* offsets   = (const float*)d_in[4];
    const float* d_inv     = (const float*)d_in[5];
    const float* z_exp_inv = (const float*)d_in[6];
    const float* c_inv     = (const float*)d_in[7];
    const float* exp_inv   = (const float*)d_in[8];
    float* out = (float*)d_out;

    const int N = in_sizes[0] / 3;
    const int E = in_sizes[2] / 2;
    const int M = in_sizes[3];

    // Workspace layout (16B-aligned regions):
    //   [0, 4096)            : mol_starts (M+1 ints)
    //   [4096, 8192)         : params (112 floats used)
    //   [8192, 8192+16N)     : pack (N float4; w = (mol<<7)|Z encoded)
    char* w = (char*)d_ws;
    int*    mol_starts = (int*)w;
    float*  params     = (float*)(w + 4096);
    float4* pack       = (float4*)(w + 8192);

    scan_params_kernel<<<1, MAX_M, 0, stream>>>(num_atoms, M, d_inv, z_exp_inv,
                                                c_inv, exp_inv, mol_starts,
                                                params, out);
    pack_kernel<<<(N + BLK - 1) / BLK, BLK, 0, stream>>>(xyz, z, mol_starts, M, N,
                                                         pack);
    nr_main_kernel<<<NBLK, BLK, 0, stream>>>(nbrs, offsets, pack,
                                             params, out, E, M);
}